// Round 1
// baseline (699.094 us; speedup 1.0000x reference)
//
#include <hip/hip_runtime.h>
#include <stdint.h>

#define N_NODES 50000
#define N_EDGES 400000
#define MPAD    50048   // 391 * 128

typedef __bf16 bf16x8 __attribute__((ext_vector_type(8)));
typedef float  f32x4  __attribute__((ext_vector_type(4)));
typedef unsigned short ushort_t;
typedef unsigned int   uint_t;

// ---------- bf16 helpers (RNE) ----------
__device__ __forceinline__ ushort_t f2b(float f){
    uint_t x = __float_as_uint(f);
    x += 0x7FFFu + ((x >> 16) & 1u);
    return (ushort_t)(x >> 16);
}
__device__ __forceinline__ float b2f(ushort_t h){
    return __uint_as_float(((uint_t)h) << 16);
}

// ---------- CSR build ----------
__global__ void zero_two(int* a, int* b, int n){
    int i = blockIdx.x * blockDim.x + threadIdx.x;
    if (i < n){ a[i] = 0; b[i] = 0; }
}

__global__ void hist_kernel(const int* __restrict__ dst, int* __restrict__ deg, int E){
    int i = blockIdx.x * blockDim.x + threadIdx.x;
    if (i < E) atomicAdd(&deg[dst[i]], 1);
}

// single block, 1024 threads; chunked sequential + block scan of per-thread totals
__global__ void scan_kernel(const int* __restrict__ deg, int* __restrict__ offs, int n){
    __shared__ int buf[1024];
    int t = threadIdx.x;
    int C = (n + 1023) >> 10;
    int lo = t * C; if (lo > n) lo = n;
    int hi = lo + C; if (hi > n) hi = n;
    int s = 0;
    for (int i = lo; i < hi; i++) s += deg[i];
    buf[t] = s; __syncthreads();
    for (int off = 1; off < 1024; off <<= 1){
        int v = (t >= off) ? buf[t - off] : 0;
        __syncthreads();
        buf[t] += v;
        __syncthreads();
    }
    int run = buf[t] - s;          // exclusive prefix
    for (int i = lo; i < hi; i++){ offs[i] = run; run += deg[i]; }
    if (t == 1023) offs[n] = buf[1023];
}

__global__ void fill_kernel(const int* __restrict__ src, const int* __restrict__ dst,
                            const int* __restrict__ offs, int* __restrict__ cursor,
                            int* __restrict__ nbr, int E){
    int i = blockIdx.x * blockDim.x + threadIdx.x;
    if (i < E){
        int d = dst[i];
        int p = atomicAdd(&cursor[d], 1);
        nbr[offs[d] + p] = src[i];
    }
}

// ---------- dtype conversion ----------
__global__ void f2b_kernel(const float4* __restrict__ in, ushort4* __restrict__ out, int n4){
    int i = blockIdx.x * blockDim.x + threadIdx.x;
    if (i < n4){
        float4 v = in[i];
        ushort4 o; o.x = f2b(v.x); o.y = f2b(v.y); o.z = f2b(v.z); o.w = f2b(v.w);
        out[i] = o;
    }
}

// W [K,N] fp32 -> Wt [N,K] bf16 (coalesced writes)
__global__ void wtrans_kernel(const float* __restrict__ W, ushort_t* __restrict__ Wt,
                              int K, int N){
    int i = blockIdx.x * blockDim.x + threadIdx.x;   // i = n*K + k
    if (i < K * N){
        int n = i / K, k = i - n * K;
        Wt[i] = f2b(W[k * N + n]);
    }
}

// ---------- GEMM: C[M,N] = A[M,K] @ Bt[N,K]^T, bf16 in, bf16 out, fp32 acc ----------
__device__ __forceinline__ void load16(const void* g, void* l){
    __builtin_amdgcn_global_load_lds((const __attribute__((address_space(1))) void*)g,
                                     (__attribute__((address_space(3))) void*)l, 16, 0, 0);
}

__global__ __launch_bounds__(256) void gemm_bt(const ushort_t* __restrict__ A,
                                               const ushort_t* __restrict__ Bt,
                                               ushort_t* __restrict__ C,
                                               int N, int K){
    __shared__ ushort_t As[128 * 32];   // 8 KB, row-major [row][k]
    __shared__ ushort_t Bs[128 * 32];   // 8 KB, row-major [n][k]
    const int tid  = threadIdx.x, lane = tid & 63, wave = tid >> 6;
    const int bm = blockIdx.x, bn = blockIdx.y;
    const int fr = lane & 15;           // fragment row within 16
    const int fk = (lane >> 4) * 8;     // fragment k-offset within 32
    const int wm = (wave >> 1) * 64, wn = (wave & 1) * 64;
    f32x4 acc[4][4] = {};

    const int s0 = wave * 2 * 64 + lane;   // staging slot base for this wave
    for (int kt = 0; kt < K; kt += 32){
        __syncthreads();
        #pragma unroll
        for (int i = 0; i < 2; i++){
            int s = s0 + i * 64;              // 0..511 (16 B each)
            int row = s >> 2, col = (s & 3) * 8;
            load16(A  + (size_t)(bm * 128 + row) * K + kt + col, (char*)As + s * 16);
            load16(Bt + (size_t)(bn * 128 + row) * K + kt + col, (char*)Bs + s * 16);
        }
        __syncthreads();   // drains vmcnt(0): global_load_lds complete
        bf16x8 af[4], bf[4];
        #pragma unroll
        for (int t = 0; t < 4; t++){
            af[t] = *(const bf16x8*)(const void*)(As + (wm + t * 16 + fr) * 32 + fk);
            bf[t] = *(const bf16x8*)(const void*)(Bs + (wn + t * 16 + fr) * 32 + fk);
        }
        #pragma unroll
        for (int tm = 0; tm < 4; tm++)
            #pragma unroll
            for (int tn = 0; tn < 4; tn++)
                acc[tm][tn] = __builtin_amdgcn_mfma_f32_16x16x32_bf16(
                                  af[tm], bf[tn], acc[tm][tn], 0, 0, 0);
    }
    // epilogue: C/D layout col=lane&15, row=(lane>>4)*4+reg  [m89-verified]
    const int r0 = (lane >> 4) * 4, c0 = lane & 15;
    #pragma unroll
    for (int tm = 0; tm < 4; tm++){
        #pragma unroll
        for (int tn = 0; tn < 4; tn++){
            int rbase = bm * 128 + wm + tm * 16 + r0;
            int cidx  = bn * 128 + wn + tn * 16 + c0;
            #pragma unroll
            for (int reg = 0; reg < 4; reg++)
                C[(size_t)(rbase + reg) * N + cidx] = f2b(acc[tm][tn][reg]);
        }
    }
}

// ---------- aggregation: H[v] = relu((sum Y[nbr] + Y[v]) / (deg+1) + b), bf16 out ----------
__global__ void agg_relu_kernel(const ushort_t* __restrict__ Y, const int* __restrict__ offs,
                                const int* __restrict__ nbr, const float* __restrict__ bias,
                                ushort_t* __restrict__ H, int d){
    int v = blockIdx.x;
    int t = threadIdx.x;                 // blockDim = d/2
    int base = v * d + 2 * t;
    uint_t y = *(const uint_t*)(const void*)(Y + base);
    float ax = b2f((ushort_t)(y & 0xffff)), ay = b2f((ushort_t)(y >> 16));
    int beg = offs[v], end = offs[v + 1];
    for (int i = beg; i < end; i++){
        int u = nbr[i];
        uint_t yu = *(const uint_t*)(const void*)(Y + u * d + 2 * t);
        ax += b2f((ushort_t)(yu & 0xffff));
        ay += b2f((ushort_t)(yu >> 16));
    }
    float inv = 1.0f / (float)(end - beg + 1);
    float2 bb = ((const float2*)bias)[t];
    float rx = ax * inv + bb.x, ry = ay * inv + bb.y;
    rx = rx > 0.f ? rx : 0.f;
    ry = ry > 0.f ? ry : 0.f;
    *(uint_t*)(void*)(H + base) = (uint_t)f2b(rx) | ((uint_t)f2b(ry) << 16);
}

// final layer: fp32 out, no relu
__global__ void agg_out_kernel(const ushort_t* __restrict__ Y, const int* __restrict__ offs,
                               const int* __restrict__ nbr, const float* __restrict__ bias,
                               float* __restrict__ out, int d){
    int v = blockIdx.x;
    int t = threadIdx.x;                 // blockDim = d/2
    int base = v * d + 2 * t;
    uint_t y = *(const uint_t*)(const void*)(Y + base);
    float ax = b2f((ushort_t)(y & 0xffff)), ay = b2f((ushort_t)(y >> 16));
    int beg = offs[v], end = offs[v + 1];
    for (int i = beg; i < end; i++){
        int u = nbr[i];
        uint_t yu = *(const uint_t*)(const void*)(Y + u * d + 2 * t);
        ax += b2f((ushort_t)(yu & 0xffff));
        ay += b2f((ushort_t)(yu >> 16));
    }
    float inv = 1.0f / (float)(end - beg + 1);
    float2 bb = ((const float2*)bias)[t];
    float2 r; r.x = ax * inv + bb.x; r.y = ay * inv + bb.y;
    ((float2*)out)[v * (d / 2) + t] = r;
}

extern "C" void kernel_launch(void* const* d_in, const int* in_sizes, int n_in,
                              void* d_out, int out_size, void* d_ws, size_t ws_size,
                              hipStream_t stream) {
    const float* feats = (const float*)d_in[0];
    const int*   src   = (const int*)  d_in[1];
    const int*   dst   = (const int*)  d_in[2];
    const float* W0    = (const float*)d_in[3];
    const float* b0    = (const float*)d_in[4];
    const float* W1    = (const float*)d_in[5];
    const float* b1    = (const float*)d_in[6];
    const float* W2    = (const float*)d_in[7];
    const float* b2    = (const float*)d_in[8];
    float* out = (float*)d_out;

    char* w = (char*)d_ws;
    ushort_t* Abuf = (ushort_t*)w;  w += (size_t)MPAD * 512 * 2;   // 51.25 MB
    ushort_t* Ybuf = (ushort_t*)w;  w += (size_t)MPAD * 512 * 2;   // 51.25 MB
    ushort_t* W0t  = (ushort_t*)w;  w += 512 * 512 * 2;
    ushort_t* W1t  = (ushort_t*)w;  w += 512 * 512 * 2;
    ushort_t* W2t  = (ushort_t*)w;  w += 256 * 512 * 2;
    int* deg    = (int*)w;          w += 50048 * 4;
    int* offs   = (int*)w;          w += 50056 * 4;
    int* cursor = (int*)w;          w += 50048 * 4;
    int* nbr    = (int*)w;          w += (size_t)N_EDGES * 4;
    // total ~106 MB

    // CSR build (re-done every launch; ws is poisoned)
    zero_two<<<(N_NODES + 255) / 256, 256, 0, stream>>>(deg, cursor, N_NODES);
    hist_kernel<<<(N_EDGES + 255) / 256, 256, 0, stream>>>(dst, deg, N_EDGES);
    scan_kernel<<<1, 1024, 0, stream>>>(deg, offs, N_NODES);
    fill_kernel<<<(N_EDGES + 255) / 256, 256, 0, stream>>>(src, dst, offs, cursor, nbr, N_EDGES);

    // conversions
    int n4 = N_NODES * 512 / 4;
    f2b_kernel<<<(n4 + 255) / 256, 256, 0, stream>>>((const float4*)feats, (ushort4*)Abuf, n4);
    wtrans_kernel<<<(512 * 512 + 255) / 256, 256, 0, stream>>>(W0, W0t, 512, 512);
    wtrans_kernel<<<(512 * 512 + 255) / 256, 256, 0, stream>>>(W1, W1t, 512, 512);
    wtrans_kernel<<<(512 * 256 + 255) / 256, 256, 0, stream>>>(W2, W2t, 512, 256);

    dim3 g01(MPAD / 128, 512 / 128);
    dim3 g2 (MPAD / 128, 256 / 128);

    // layer 0: Y = A @ W0t^T ; A' = relu((agg Y + Y)/(deg+1) + b0)
    gemm_bt<<<g01, 256, 0, stream>>>(Abuf, W0t, Ybuf, 512, 512);
    agg_relu_kernel<<<N_NODES, 256, 0, stream>>>(Ybuf, offs, nbr, b0, Abuf, 512);
    // layer 1
    gemm_bt<<<g01, 256, 0, stream>>>(Abuf, W1t, Ybuf, 512, 512);
    agg_relu_kernel<<<N_NODES, 256, 0, stream>>>(Ybuf, offs, nbr, b1, Abuf, 512);
    // layer 2 (no relu, fp32 out)
    gemm_bt<<<g2, 256, 0, stream>>>(Abuf, W2t, Ybuf, 256, 512);
    agg_out_kernel<<<N_NODES, 128, 0, stream>>>(Ybuf, offs, nbr, b2, out, 256);
}

// Round 2
// 607.584 us; speedup vs baseline: 1.1506x; 1.1506x over previous
//
#include <hip/hip_runtime.h>
#include <stdint.h>

#define N_NODES 50000
#define N_EDGES 400000
#define MPAD    50048   // 391 * 128

typedef __bf16 bf16x8 __attribute__((ext_vector_type(8)));
typedef float  f32x4  __attribute__((ext_vector_type(4)));
typedef unsigned short ushort_t;
typedef unsigned int   uint_t;

// ---------- bf16 helpers (RNE) ----------
__device__ __forceinline__ ushort_t f2b(float f){
    uint_t x = __float_as_uint(f);
    x += 0x7FFFu + ((x >> 16) & 1u);
    return (ushort_t)(x >> 16);
}
__device__ __forceinline__ float b2f(ushort_t h){
    return __uint_as_float(((uint_t)h) << 16);
}

// ---------- CSR build ----------
__global__ void zero_two(int* a, int* b, int n){
    int i = blockIdx.x * blockDim.x + threadIdx.x;
    if (i < n){ a[i] = 0; b[i] = 0; }
}

__global__ void hist_kernel(const int* __restrict__ dst, int* __restrict__ deg, int E){
    int i = blockIdx.x * blockDim.x + threadIdx.x;
    if (i < E) atomicAdd(&deg[dst[i]], 1);
}

// single block, 1024 threads; chunked sequential + block scan of per-thread totals
__global__ void scan_kernel(const int* __restrict__ deg, int* __restrict__ offs, int n){
    __shared__ int buf[1024];
    int t = threadIdx.x;
    int C = (n + 1023) >> 10;
    int lo = t * C; if (lo > n) lo = n;
    int hi = lo + C; if (hi > n) hi = n;
    int s = 0;
    for (int i = lo; i < hi; i++) s += deg[i];
    buf[t] = s; __syncthreads();
    for (int off = 1; off < 1024; off <<= 1){
        int v = (t >= off) ? buf[t - off] : 0;
        __syncthreads();
        buf[t] += v;
        __syncthreads();
    }
    int run = buf[t] - s;          // exclusive prefix
    for (int i = lo; i < hi; i++){ offs[i] = run; run += deg[i]; }
    if (t == 1023) offs[n] = buf[1023];
}

__global__ void fill_kernel(const int* __restrict__ src, const int* __restrict__ dst,
                            const int* __restrict__ offs, int* __restrict__ cursor,
                            int* __restrict__ nbr, int E){
    int i = blockIdx.x * blockDim.x + threadIdx.x;
    if (i < E){
        int d = dst[i];
        int p = atomicAdd(&cursor[d], 1);
        nbr[offs[d] + p] = src[i];
    }
}

// ---------- dtype conversion ----------
__global__ void f2b_kernel(const float4* __restrict__ in, ushort4* __restrict__ out, int n4){
    int i = blockIdx.x * blockDim.x + threadIdx.x;
    if (i < n4){
        float4 v = in[i];
        ushort4 o; o.x = f2b(v.x); o.y = f2b(v.y); o.z = f2b(v.z); o.w = f2b(v.w);
        out[i] = o;
    }
}

// W [K,N] fp32 -> Wt [N,K] bf16 (coalesced writes)
__global__ void wtrans_kernel(const float* __restrict__ W, ushort_t* __restrict__ Wt,
                              int K, int N){
    int i = blockIdx.x * blockDim.x + threadIdx.x;   // i = n*K + k
    if (i < K * N){
        int n = i / K, k = i - n * K;
        Wt[i] = f2b(W[k * N + n]);
    }
}

// ---------- GEMM: C[M,N] = A[M,K] @ Bt[N,K]^T, bf16 in, bf16 out, fp32 acc ----------
__device__ __forceinline__ void load16(const void* g, void* l){
    __builtin_amdgcn_global_load_lds((const __attribute__((address_space(1))) void*)g,
                                     (__attribute__((address_space(3))) void*)l, 16, 0, 0);
}

__global__ __launch_bounds__(256) void gemm_bt(const ushort_t* __restrict__ A,
                                               const ushort_t* __restrict__ Bt,
                                               ushort_t* __restrict__ C,
                                               int N, int K){
    __shared__ ushort_t As[128 * 32];   // 8 KB, row-major [row][k]
    __shared__ ushort_t Bs[128 * 32];   // 8 KB, row-major [n][k]
    const int tid  = threadIdx.x, lane = tid & 63, wave = tid >> 6;
    const int bm = blockIdx.x, bn = blockIdx.y;
    const int fr = lane & 15;           // fragment row within 16
    const int fk = (lane >> 4) * 8;     // fragment k-offset within 32
    const int wm = (wave >> 1) * 64, wn = (wave & 1) * 64;
    f32x4 acc[4][4] = {};

    const int s0 = wave * 2 * 64 + lane;   // staging slot base for this wave
    for (int kt = 0; kt < K; kt += 32){
        __syncthreads();
        #pragma unroll
        for (int i = 0; i < 2; i++){
            int s = s0 + i * 64;              // 0..511 (16 B each)
            int row = s >> 2, col = (s & 3) * 8;
            load16(A  + (size_t)(bm * 128 + row) * K + kt + col, (char*)As + s * 16);
            load16(Bt + (size_t)(bn * 128 + row) * K + kt + col, (char*)Bs + s * 16);
        }
        __syncthreads();   // drains vmcnt(0): global_load_lds complete
        bf16x8 af[4], bf[4];
        #pragma unroll
        for (int t = 0; t < 4; t++){
            af[t] = *(const bf16x8*)(const void*)(As + (wm + t * 16 + fr) * 32 + fk);
            bf[t] = *(const bf16x8*)(const void*)(Bs + (wn + t * 16 + fr) * 32 + fk);
        }
        #pragma unroll
        for (int tm = 0; tm < 4; tm++)
            #pragma unroll
            for (int tn = 0; tn < 4; tn++)
                acc[tm][tn] = __builtin_amdgcn_mfma_f32_16x16x32_bf16(
                                  af[tm], bf[tn], acc[tm][tn], 0, 0, 0);
    }
    // epilogue: C/D layout col=lane&15, row=(lane>>4)*4+reg  [m89-verified]
    const int r0 = (lane >> 4) * 4, c0 = lane & 15;
    #pragma unroll
    for (int tm = 0; tm < 4; tm++){
        #pragma unroll
        for (int tn = 0; tn < 4; tn++){
            int rbase = bm * 128 + wm + tm * 16 + r0;
            int cidx  = bn * 128 + wn + tn * 16 + c0;
            #pragma unroll
            for (int reg = 0; reg < 4; reg++)
                C[(size_t)(rbase + reg) * N + cidx] = f2b(acc[tm][tn][reg]);
        }
    }
}

// ---------- aggregation (wave-per-node, 16B/lane, 4-edge unrolled) ----------
__device__ __forceinline__ void acc8(float* a, uint4 y){
    a[0] += b2f((ushort_t)(y.x & 0xffff)); a[1] += b2f((ushort_t)(y.x >> 16));
    a[2] += b2f((ushort_t)(y.y & 0xffff)); a[3] += b2f((ushort_t)(y.y >> 16));
    a[4] += b2f((ushort_t)(y.z & 0xffff)); a[5] += b2f((ushort_t)(y.z >> 16));
    a[6] += b2f((ushort_t)(y.w & 0xffff)); a[7] += b2f((ushort_t)(y.w >> 16));
}
__device__ __forceinline__ void acc4(float* a, uint2 y){
    a[0] += b2f((ushort_t)(y.x & 0xffff)); a[1] += b2f((ushort_t)(y.x >> 16));
    a[2] += b2f((ushort_t)(y.y & 0xffff)); a[3] += b2f((ushort_t)(y.y >> 16));
}

// H[v] = relu((sum Y[nbr] + Y[v]) / (deg+1) + b), d=512, bf16 out
// wave per node: lane covers elems [lane*8, lane*8+8)
__global__ __launch_bounds__(256) void agg_relu_kernel(
        const ushort_t* __restrict__ Y, const int* __restrict__ offs,
        const int* __restrict__ nbr, const float* __restrict__ bias,
        ushort_t* __restrict__ H){
    const int lane = threadIdx.x & 63, wave = threadIdx.x >> 6;
    const int v = blockIdx.x * 4 + wave;
    const int off = lane * 8;
    float a[8];
    {   uint4 y = *(const uint4*)(const void*)(Y + (size_t)v * 512 + off);
        a[0] = b2f((ushort_t)(y.x & 0xffff)); a[1] = b2f((ushort_t)(y.x >> 16));
        a[2] = b2f((ushort_t)(y.y & 0xffff)); a[3] = b2f((ushort_t)(y.y >> 16));
        a[4] = b2f((ushort_t)(y.z & 0xffff)); a[5] = b2f((ushort_t)(y.z >> 16));
        a[6] = b2f((ushort_t)(y.w & 0xffff)); a[7] = b2f((ushort_t)(y.w >> 16)); }
    const int beg = offs[v], end = offs[v + 1];
    int i = beg;
    for (; i + 4 <= end; i += 4){
        int u0 = nbr[i], u1 = nbr[i+1], u2 = nbr[i+2], u3 = nbr[i+3];
        uint4 y0 = *(const uint4*)(const void*)(Y + (size_t)u0 * 512 + off);
        uint4 y1 = *(const uint4*)(const void*)(Y + (size_t)u1 * 512 + off);
        uint4 y2 = *(const uint4*)(const void*)(Y + (size_t)u2 * 512 + off);
        uint4 y3 = *(const uint4*)(const void*)(Y + (size_t)u3 * 512 + off);
        acc8(a, y0); acc8(a, y1); acc8(a, y2); acc8(a, y3);
    }
    for (; i < end; i++){
        int u = nbr[i];
        uint4 y = *(const uint4*)(const void*)(Y + (size_t)u * 512 + off);
        acc8(a, y);
    }
    const float inv = 1.0f / (float)(end - beg + 1);
    float4 bb0 = ((const float4*)bias)[lane * 2];
    float4 bb1 = ((const float4*)bias)[lane * 2 + 1];
    float r[8];
    r[0] = a[0]*inv + bb0.x; r[1] = a[1]*inv + bb0.y;
    r[2] = a[2]*inv + bb0.z; r[3] = a[3]*inv + bb0.w;
    r[4] = a[4]*inv + bb1.x; r[5] = a[5]*inv + bb1.y;
    r[6] = a[6]*inv + bb1.z; r[7] = a[7]*inv + bb1.w;
    #pragma unroll
    for (int j = 0; j < 8; j++) r[j] = r[j] > 0.f ? r[j] : 0.f;
    uint4 o;
    o.x = (uint_t)f2b(r[0]) | ((uint_t)f2b(r[1]) << 16);
    o.y = (uint_t)f2b(r[2]) | ((uint_t)f2b(r[3]) << 16);
    o.z = (uint_t)f2b(r[4]) | ((uint_t)f2b(r[5]) << 16);
    o.w = (uint_t)f2b(r[6]) | ((uint_t)f2b(r[7]) << 16);
    *(uint4*)(void*)(H + (size_t)v * 512 + off) = o;
}

// final layer: d=256, fp32 out, no relu. wave per node, lane covers 4 elems (8B in, 16B out)
__global__ __launch_bounds__(256) void agg_out_kernel(
        const ushort_t* __restrict__ Y, const int* __restrict__ offs,
        const int* __restrict__ nbr, const float* __restrict__ bias,
        float* __restrict__ out){
    const int lane = threadIdx.x & 63, wave = threadIdx.x >> 6;
    const int v = blockIdx.x * 4 + wave;
    const int off = lane * 4;
    float a[4];
    {   uint2 y = *(const uint2*)(const void*)(Y + (size_t)v * 256 + off);
        a[0] = b2f((ushort_t)(y.x & 0xffff)); a[1] = b2f((ushort_t)(y.x >> 16));
        a[2] = b2f((ushort_t)(y.y & 0xffff)); a[3] = b2f((ushort_t)(y.y >> 16)); }
    const int beg = offs[v], end = offs[v + 1];
    int i = beg;
    for (; i + 4 <= end; i += 4){
        int u0 = nbr[i], u1 = nbr[i+1], u2 = nbr[i+2], u3 = nbr[i+3];
        uint2 y0 = *(const uint2*)(const void*)(Y + (size_t)u0 * 256 + off);
        uint2 y1 = *(const uint2*)(const void*)(Y + (size_t)u1 * 256 + off);
        uint2 y2 = *(const uint2*)(const void*)(Y + (size_t)u2 * 256 + off);
        uint2 y3 = *(const uint2*)(const void*)(Y + (size_t)u3 * 256 + off);
        acc4(a, y0); acc4(a, y1); acc4(a, y2); acc4(a, y3);
    }
    for (; i < end; i++){
        int u = nbr[i];
        uint2 y = *(const uint2*)(const void*)(Y + (size_t)u * 256 + off);
        acc4(a, y);
    }
    const float inv = 1.0f / (float)(end - beg + 1);
    float4 bb = ((const float4*)bias)[lane];
    float4 r;
    r.x = a[0]*inv + bb.x; r.y = a[1]*inv + bb.y;
    r.z = a[2]*inv + bb.z; r.w = a[3]*inv + bb.w;
    ((float4*)out)[v * 64 + lane] = r;
}

extern "C" void kernel_launch(void* const* d_in, const int* in_sizes, int n_in,
                              void* d_out, int out_size, void* d_ws, size_t ws_size,
                              hipStream_t stream) {
    const float* feats = (const float*)d_in[0];
    const int*   src   = (const int*)  d_in[1];
    const int*   dst   = (const int*)  d_in[2];
    const float* W0    = (const float*)d_in[3];
    const float* b0    = (const float*)d_in[4];
    const float* W1    = (const float*)d_in[5];
    const float* b1    = (const float*)d_in[6];
    const float* W2    = (const float*)d_in[7];
    const float* b2    = (const float*)d_in[8];
    float* out = (float*)d_out;

    char* w = (char*)d_ws;
    ushort_t* Abuf = (ushort_t*)w;  w += (size_t)MPAD * 512 * 2;   // 51.25 MB
    ushort_t* Ybuf = (ushort_t*)w;  w += (size_t)MPAD * 512 * 2;   // 51.25 MB
    ushort_t* W0t  = (ushort_t*)w;  w += 512 * 512 * 2;
    ushort_t* W1t  = (ushort_t*)w;  w += 512 * 512 * 2;
    ushort_t* W2t  = (ushort_t*)w;  w += 256 * 512 * 2;
    int* deg    = (int*)w;          w += 50048 * 4;
    int* offs   = (int*)w;          w += 50056 * 4;
    int* cursor = (int*)w;          w += 50048 * 4;
    int* nbr    = (int*)w;          w += (size_t)N_EDGES * 4;
    // total ~106 MB

    // CSR build (re-done every launch; ws is poisoned)
    zero_two<<<(N_NODES + 255) / 256, 256, 0, stream>>>(deg, cursor, N_NODES);
    hist_kernel<<<(N_EDGES + 255) / 256, 256, 0, stream>>>(dst, deg, N_EDGES);
    scan_kernel<<<1, 1024, 0, stream>>>(deg, offs, N_NODES);
    fill_kernel<<<(N_EDGES + 255) / 256, 256, 0, stream>>>(src, dst, offs, cursor, nbr, N_EDGES);

    // conversions
    int n4 = N_NODES * 512 / 4;
    f2b_kernel<<<(n4 + 255) / 256, 256, 0, stream>>>((const float4*)feats, (ushort4*)Abuf, n4);
    wtrans_kernel<<<(512 * 512 + 255) / 256, 256, 0, stream>>>(W0, W0t, 512, 512);
    wtrans_kernel<<<(512 * 512 + 255) / 256, 256, 0, stream>>>(W1, W1t, 512, 512);
    wtrans_kernel<<<(512 * 256 + 255) / 256, 256, 0, stream>>>(W2, W2t, 512, 256);

    dim3 g01(MPAD / 128, 512 / 128);
    dim3 g2 (MPAD / 128, 256 / 128);

    // layer 0: Y = A @ W0t^T ; A' = relu((agg Y + Y)/(deg+1) + b0)
    gemm_bt<<<g01, 256, 0, stream>>>(Abuf, W0t, Ybuf, 512, 512);
    agg_relu_kernel<<<N_NODES / 4, 256, 0, stream>>>(Ybuf, offs, nbr, b0, Abuf);
    // layer 1
    gemm_bt<<<g01, 256, 0, stream>>>(Abuf, W1t, Ybuf, 512, 512);
    agg_relu_kernel<<<N_NODES / 4, 256, 0, stream>>>(Ybuf, offs, nbr, b1, Abuf);
    // layer 2 (no relu, fp32 out)
    gemm_bt<<<g2, 256, 0, stream>>>(Abuf, W2t, Ybuf, 256, 512);
    agg_out_kernel<<<N_NODES / 4, 256, 0, stream>>>(Ybuf, offs, nbr, b2, out);
}

// Round 3
// 542.553 us; speedup vs baseline: 1.2885x; 1.1199x over previous
//
#include <hip/hip_runtime.h>
#include <stdint.h>

#define N_NODES 50000
#define N_EDGES 400000
#define MPAD    50048   // 391 * 128
#define SCAN_B  49      // ceil(50000/1024)

typedef __bf16 bf16x8 __attribute__((ext_vector_type(8)));
typedef float  f32x4  __attribute__((ext_vector_type(4)));
typedef unsigned short ushort_t;
typedef unsigned int   uint_t;

// ---------- bf16 helpers (RNE) ----------
__device__ __forceinline__ ushort_t f2b(float f){
    uint_t x = __float_as_uint(f);
    x += 0x7FFFu + ((x >> 16) & 1u);
    return (ushort_t)(x >> 16);
}
__device__ __forceinline__ float b2f(ushort_t h){
    return __uint_as_float(((uint_t)h) << 16);
}

// ---------- CSR build ----------
__global__ void zero_two(int* a, int* b, int n){
    int i = blockIdx.x * blockDim.x + threadIdx.x;
    if (i < n){ a[i] = 0; b[i] = 0; }
}

__global__ void hist_kernel(const int* __restrict__ dst, int* __restrict__ deg, int E){
    int i = blockIdx.x * blockDim.x + threadIdx.x;
    if (i < E) atomicAdd(&deg[dst[i]], 1);
}

// hierarchical scan, stage 1: per-block exclusive scan + block totals
__global__ __launch_bounds__(1024) void blk_scan_kernel(
        const int* __restrict__ deg, int* __restrict__ offs,
        int* __restrict__ bsum, int n){
    __shared__ int buf[1024];
    const int t = threadIdx.x, b = blockIdx.x;
    const int i = b * 1024 + t;
    int v = (i < n) ? deg[i] : 0;
    buf[t] = v; __syncthreads();
    for (int off = 1; off < 1024; off <<= 1){
        int x = (t >= off) ? buf[t - off] : 0;
        __syncthreads();
        buf[t] += x;
        __syncthreads();
    }
    if (i < n) offs[i] = buf[t] - v;         // local exclusive prefix
    if (t == 1023) bsum[b] = buf[1023];      // block total
}

// stage 2: one wave scans the 49 block totals (exclusive)
__global__ void bsum_scan_kernel(int* __restrict__ bsum, int nb){
    int t = threadIdx.x;                      // 64 threads
    int orig = (t < nb) ? bsum[t] : 0;
    int v = orig;
    #pragma unroll
    for (int off = 1; off < 64; off <<= 1){
        int x = __shfl_up(v, off, 64);
        if (t >= off) v += x;
    }
    if (t < nb) bsum[t] = v - orig;           // exclusive
}

// stage 3: add block offsets; set offs[n] = E (constant: every edge lands in [0,n))
__global__ __launch_bounds__(1024) void add_off_kernel(
        int* __restrict__ offs, const int* __restrict__ bsum, int n){
    int i = blockIdx.x * 1024 + threadIdx.x;
    if (i < n) offs[i] += bsum[blockIdx.x];
    if (i == 0) offs[n] = N_EDGES;
}

__global__ void fill_kernel(const int* __restrict__ src, const int* __restrict__ dst,
                            const int* __restrict__ offs, int* __restrict__ cursor,
                            int* __restrict__ nbr, int E){
    int i = blockIdx.x * blockDim.x + threadIdx.x;
    if (i < E){
        int d = dst[i];
        int p = atomicAdd(&cursor[d], 1);
        nbr[offs[d] + p] = src[i];
    }
}

// ---------- dtype conversion ----------
__global__ void f2b_kernel(const float4* __restrict__ in, ushort4* __restrict__ out, int n4){
    int i = blockIdx.x * blockDim.x + threadIdx.x;
    if (i < n4){
        float4 v = in[i];
        ushort4 o; o.x = f2b(v.x); o.y = f2b(v.y); o.z = f2b(v.z); o.w = f2b(v.w);
        out[i] = o;
    }
}

// W [K,N] fp32 -> Wt [N,K] bf16 (coalesced writes)
__global__ void wtrans_kernel(const float* __restrict__ W, ushort_t* __restrict__ Wt,
                              int K, int N){
    int i = blockIdx.x * blockDim.x + threadIdx.x;   // i = n*K + k
    if (i < K * N){
        int n = i / K, k = i - n * K;
        Wt[i] = f2b(W[k * N + n]);
    }
}

// ---------- GEMM: C[M,N] = A[M,K] @ Bt[N,K]^T, bf16 in, bf16 out, fp32 acc ----------
__device__ __forceinline__ void load16(const void* g, void* l){
    __builtin_amdgcn_global_load_lds((const __attribute__((address_space(1))) void*)g,
                                     (__attribute__((address_space(3))) void*)l, 16, 0, 0);
}

__global__ __launch_bounds__(256) void gemm_bt(const ushort_t* __restrict__ A,
                                               const ushort_t* __restrict__ Bt,
                                               ushort_t* __restrict__ C,
                                               int N, int K){
    __shared__ ushort_t As[128 * 32];   // 8 KB, row-major [row][k]
    __shared__ ushort_t Bs[128 * 32];   // 8 KB, row-major [n][k]
    const int tid  = threadIdx.x, lane = tid & 63, wave = tid >> 6;
    const int bm = blockIdx.x, bn = blockIdx.y;
    const int fr = lane & 15;           // fragment row within 16
    const int fk = (lane >> 4) * 8;     // fragment k-offset within 32
    const int wm = (wave >> 1) * 64, wn = (wave & 1) * 64;
    f32x4 acc[4][4] = {};

    const int s0 = wave * 2 * 64 + lane;   // staging slot base for this wave
    for (int kt = 0; kt < K; kt += 32){
        __syncthreads();
        #pragma unroll
        for (int i = 0; i < 2; i++){
            int s = s0 + i * 64;              // 0..511 (16 B each)
            int row = s >> 2, col = (s & 3) * 8;
            load16(A  + (size_t)(bm * 128 + row) * K + kt + col, (char*)As + s * 16);
            load16(Bt + (size_t)(bn * 128 + row) * K + kt + col, (char*)Bs + s * 16);
        }
        __syncthreads();   // drains vmcnt(0): global_load_lds complete
        bf16x8 af[4], bf[4];
        #pragma unroll
        for (int t = 0; t < 4; t++){
            af[t] = *(const bf16x8*)(const void*)(As + (wm + t * 16 + fr) * 32 + fk);
            bf[t] = *(const bf16x8*)(const void*)(Bs + (wn + t * 16 + fr) * 32 + fk);
        }
        #pragma unroll
        for (int tm = 0; tm < 4; tm++)
            #pragma unroll
            for (int tn = 0; tn < 4; tn++)
                acc[tm][tn] = __builtin_amdgcn_mfma_f32_16x16x32_bf16(
                                  af[tm], bf[tn], acc[tm][tn], 0, 0, 0);
    }
    // epilogue: C/D layout col=lane&15, row=(lane>>4)*4+reg  [m89-verified]
    const int r0 = (lane >> 4) * 4, c0 = lane & 15;
    #pragma unroll
    for (int tm = 0; tm < 4; tm++){
        #pragma unroll
        for (int tn = 0; tn < 4; tn++){
            int rbase = bm * 128 + wm + tm * 16 + r0;
            int cidx  = bn * 128 + wn + tn * 16 + c0;
            #pragma unroll
            for (int reg = 0; reg < 4; reg++)
                C[(size_t)(rbase + reg) * N + cidx] = f2b(acc[tm][tn][reg]);
        }
    }
}

// ---------- aggregation (wave-per-node, 16B/lane, 4-edge unrolled) ----------
__device__ __forceinline__ void acc8(float* a, uint4 y){
    a[0] += b2f((ushort_t)(y.x & 0xffff)); a[1] += b2f((ushort_t)(y.x >> 16));
    a[2] += b2f((ushort_t)(y.y & 0xffff)); a[3] += b2f((ushort_t)(y.y >> 16));
    a[4] += b2f((ushort_t)(y.z & 0xffff)); a[5] += b2f((ushort_t)(y.z >> 16));
    a[6] += b2f((ushort_t)(y.w & 0xffff)); a[7] += b2f((ushort_t)(y.w >> 16));
}
__device__ __forceinline__ void acc4(float* a, uint2 y){
    a[0] += b2f((ushort_t)(y.x & 0xffff)); a[1] += b2f((ushort_t)(y.x >> 16));
    a[2] += b2f((ushort_t)(y.y & 0xffff)); a[3] += b2f((ushort_t)(y.y >> 16));
}

// H[v] = relu((sum Y[nbr] + Y[v]) / (deg+1) + b), d=512, bf16 out
// wave per node: lane covers elems [lane*8, lane*8+8)
__global__ __launch_bounds__(256) void agg_relu_kernel(
        const ushort_t* __restrict__ Y, const int* __restrict__ offs,
        const int* __restrict__ nbr, const float* __restrict__ bias,
        ushort_t* __restrict__ H){
    const int lane = threadIdx.x & 63, wave = threadIdx.x >> 6;
    const int v = blockIdx.x * 4 + wave;
    const int off = lane * 8;
    float a[8];
    {   uint4 y = *(const uint4*)(const void*)(Y + (size_t)v * 512 + off);
        a[0] = b2f((ushort_t)(y.x & 0xffff)); a[1] = b2f((ushort_t)(y.x >> 16));
        a[2] = b2f((ushort_t)(y.y & 0xffff)); a[3] = b2f((ushort_t)(y.y >> 16));
        a[4] = b2f((ushort_t)(y.z & 0xffff)); a[5] = b2f((ushort_t)(y.z >> 16));
        a[6] = b2f((ushort_t)(y.w & 0xffff)); a[7] = b2f((ushort_t)(y.w >> 16)); }
    const int beg = offs[v], end = offs[v + 1];
    int i = beg;
    for (; i + 4 <= end; i += 4){
        int u0 = nbr[i], u1 = nbr[i+1], u2 = nbr[i+2], u3 = nbr[i+3];
        uint4 y0 = *(const uint4*)(const void*)(Y + (size_t)u0 * 512 + off);
        uint4 y1 = *(const uint4*)(const void*)(Y + (size_t)u1 * 512 + off);
        uint4 y2 = *(const uint4*)(const void*)(Y + (size_t)u2 * 512 + off);
        uint4 y3 = *(const uint4*)(const void*)(Y + (size_t)u3 * 512 + off);
        acc8(a, y0); acc8(a, y1); acc8(a, y2); acc8(a, y3);
    }
    for (; i < end; i++){
        int u = nbr[i];
        uint4 y = *(const uint4*)(const void*)(Y + (size_t)u * 512 + off);
        acc8(a, y);
    }
    const float inv = 1.0f / (float)(end - beg + 1);
    float4 bb0 = ((const float4*)bias)[lane * 2];
    float4 bb1 = ((const float4*)bias)[lane * 2 + 1];
    float r[8];
    r[0] = a[0]*inv + bb0.x; r[1] = a[1]*inv + bb0.y;
    r[2] = a[2]*inv + bb0.z; r[3] = a[3]*inv + bb0.w;
    r[4] = a[4]*inv + bb1.x; r[5] = a[5]*inv + bb1.y;
    r[6] = a[6]*inv + bb1.z; r[7] = a[7]*inv + bb1.w;
    #pragma unroll
    for (int j = 0; j < 8; j++) r[j] = r[j] > 0.f ? r[j] : 0.f;
    uint4 o;
    o.x = (uint_t)f2b(r[0]) | ((uint_t)f2b(r[1]) << 16);
    o.y = (uint_t)f2b(r[2]) | ((uint_t)f2b(r[3]) << 16);
    o.z = (uint_t)f2b(r[4]) | ((uint_t)f2b(r[5]) << 16);
    o.w = (uint_t)f2b(r[6]) | ((uint_t)f2b(r[7]) << 16);
    *(uint4*)(void*)(H + (size_t)v * 512 + off) = o;
}

// final layer: d=256, fp32 out, no relu. wave per node, lane covers 4 elems (8B in, 16B out)
__global__ __launch_bounds__(256) void agg_out_kernel(
        const ushort_t* __restrict__ Y, const int* __restrict__ offs,
        const int* __restrict__ nbr, const float* __restrict__ bias,
        float* __restrict__ out){
    const int lane = threadIdx.x & 63, wave = threadIdx.x >> 6;
    const int v = blockIdx.x * 4 + wave;
    const int off = lane * 4;
    float a[4];
    {   uint2 y = *(const uint2*)(const void*)(Y + (size_t)v * 256 + off);
        a[0] = b2f((ushort_t)(y.x & 0xffff)); a[1] = b2f((ushort_t)(y.x >> 16));
        a[2] = b2f((ushort_t)(y.y & 0xffff)); a[3] = b2f((ushort_t)(y.y >> 16)); }
    const int beg = offs[v], end = offs[v + 1];
    int i = beg;
    for (; i + 4 <= end; i += 4){
        int u0 = nbr[i], u1 = nbr[i+1], u2 = nbr[i+2], u3 = nbr[i+3];
        uint2 y0 = *(const uint2*)(const void*)(Y + (size_t)u0 * 256 + off);
        uint2 y1 = *(const uint2*)(const void*)(Y + (size_t)u1 * 256 + off);
        uint2 y2 = *(const uint2*)(const void*)(Y + (size_t)u2 * 256 + off);
        uint2 y3 = *(const uint2*)(const void*)(Y + (size_t)u3 * 256 + off);
        acc4(a, y0); acc4(a, y1); acc4(a, y2); acc4(a, y3);
    }
    for (; i < end; i++){
        int u = nbr[i];
        uint2 y = *(const uint2*)(const void*)(Y + (size_t)u * 256 + off);
        acc4(a, y);
    }
    const float inv = 1.0f / (float)(end - beg + 1);
    float4 bb = ((const float4*)bias)[lane];
    float4 r;
    r.x = a[0]*inv + bb.x; r.y = a[1]*inv + bb.y;
    r.z = a[2]*inv + bb.z; r.w = a[3]*inv + bb.w;
    ((float4*)out)[v * 64 + lane] = r;
}

extern "C" void kernel_launch(void* const* d_in, const int* in_sizes, int n_in,
                              void* d_out, int out_size, void* d_ws, size_t ws_size,
                              hipStream_t stream) {
    const float* feats = (const float*)d_in[0];
    const int*   src   = (const int*)  d_in[1];
    const int*   dst   = (const int*)  d_in[2];
    const float* W0    = (const float*)d_in[3];
    const float* b0    = (const float*)d_in[4];
    const float* W1    = (const float*)d_in[5];
    const float* b1    = (const float*)d_in[6];
    const float* W2    = (const float*)d_in[7];
    const float* b2    = (const float*)d_in[8];
    float* out = (float*)d_out;

    char* w = (char*)d_ws;
    ushort_t* Abuf = (ushort_t*)w;  w += (size_t)MPAD * 512 * 2;   // 51.25 MB
    ushort_t* Ybuf = (ushort_t*)w;  w += (size_t)MPAD * 512 * 2;   // 51.25 MB
    ushort_t* W0t  = (ushort_t*)w;  w += 512 * 512 * 2;
    ushort_t* W1t  = (ushort_t*)w;  w += 512 * 512 * 2;
    ushort_t* W2t  = (ushort_t*)w;  w += 256 * 512 * 2;
    int* deg    = (int*)w;          w += 50048 * 4;
    int* offs   = (int*)w;          w += 50056 * 4;
    int* cursor = (int*)w;          w += 50048 * 4;
    int* nbr    = (int*)w;          w += (size_t)N_EDGES * 4;
    int* bsum   = (int*)w;          w += 64 * 4;
    // total ~106 MB

    // CSR build (re-done every launch; ws is poisoned)
    zero_two<<<(N_NODES + 255) / 256, 256, 0, stream>>>(deg, cursor, N_NODES);
    hist_kernel<<<(N_EDGES + 255) / 256, 256, 0, stream>>>(dst, deg, N_EDGES);
    blk_scan_kernel<<<SCAN_B, 1024, 0, stream>>>(deg, offs, bsum, N_NODES);
    bsum_scan_kernel<<<1, 64, 0, stream>>>(bsum, SCAN_B);
    add_off_kernel<<<SCAN_B, 1024, 0, stream>>>(offs, bsum, N_NODES);
    fill_kernel<<<(N_EDGES + 255) / 256, 256, 0, stream>>>(src, dst, offs, cursor, nbr, N_EDGES);

    // conversions
    int n4 = N_NODES * 512 / 4;
    f2b_kernel<<<(n4 + 255) / 256, 256, 0, stream>>>((const float4*)feats, (ushort4*)Abuf, n4);
    wtrans_kernel<<<(512 * 512 + 255) / 256, 256, 0, stream>>>(W0, W0t, 512, 512);
    wtrans_kernel<<<(512 * 512 + 255) / 256, 256, 0, stream>>>(W1, W1t, 512, 512);
    wtrans_kernel<<<(512 * 256 + 255) / 256, 256, 0, stream>>>(W2, W2t, 512, 256);

    dim3 g01(MPAD / 128, 512 / 128);
    dim3 g2 (MPAD / 128, 256 / 128);

    // layer 0: Y = A @ W0t^T ; A' = relu((agg Y + Y)/(deg+1) + b0)
    gemm_bt<<<g01, 256, 0, stream>>>(Abuf, W0t, Ybuf, 512, 512);
    agg_relu_kernel<<<N_NODES / 4, 256, 0, stream>>>(Ybuf, offs, nbr, b0, Abuf);
    // layer 1
    gemm_bt<<<g01, 256, 0, stream>>>(Abuf, W1t, Ybuf, 512, 512);
    agg_relu_kernel<<<N_NODES / 4, 256, 0, stream>>>(Ybuf, offs, nbr, b1, Abuf);
    // layer 2 (no relu, fp32 out)
    gemm_bt<<<g2, 256, 0, stream>>>(Abuf, W2t, Ybuf, 256, 512);
    agg_out_kernel<<<N_NODES / 4, 256, 0, stream>>>(Ybuf, offs, nbr, b2, out);
}

// Round 4
// 518.605 us; speedup vs baseline: 1.3480x; 1.0462x over previous
//
#include <hip/hip_runtime.h>
#include <stdint.h>

#define N_NODES 50000
#define N_EDGES 400000
#define MPAD    50048   // 391 * 128
#define SCAN_B  49      // ceil(50000/1024)

typedef __bf16 bf16x8 __attribute__((ext_vector_type(8)));
typedef float  f32x4  __attribute__((ext_vector_type(4)));
typedef unsigned short ushort_t;
typedef unsigned int   uint_t;

// ---------- bf16 helpers (RNE) ----------
__device__ __forceinline__ ushort_t f2b(float f){
    uint_t x = __float_as_uint(f);
    x += 0x7FFFu + ((x >> 16) & 1u);
    return (ushort_t)(x >> 16);
}
__device__ __forceinline__ float b2f(ushort_t h){
    return __uint_as_float(((uint_t)h) << 16);
}

// ---------- CSR build ----------
__global__ void zero_two(int* a, int* b, int n){
    int i = blockIdx.x * blockDim.x + threadIdx.x;
    if (i < n){ a[i] = 0; b[i] = 0; }
}

__global__ void hist_kernel(const int* __restrict__ dst, int* __restrict__ deg, int E){
    int i = blockIdx.x * blockDim.x + threadIdx.x;
    if (i < E) atomicAdd(&deg[dst[i]], 1);
}

// hierarchical scan, stage 1: per-block exclusive scan + block totals
__global__ __launch_bounds__(1024) void blk_scan_kernel(
        const int* __restrict__ deg, int* __restrict__ offs,
        int* __restrict__ bsum, int n){
    __shared__ int buf[1024];
    const int t = threadIdx.x, b = blockIdx.x;
    const int i = b * 1024 + t;
    int v = (i < n) ? deg[i] : 0;
    buf[t] = v; __syncthreads();
    for (int off = 1; off < 1024; off <<= 1){
        int x = (t >= off) ? buf[t - off] : 0;
        __syncthreads();
        buf[t] += x;
        __syncthreads();
    }
    if (i < n) offs[i] = buf[t] - v;         // local exclusive prefix
    if (t == 1023) bsum[b] = buf[1023];      // block total
}

// stage 2: one wave scans the 49 block totals (exclusive)
__global__ void bsum_scan_kernel(int* __restrict__ bsum, int nb){
    int t = threadIdx.x;                      // 64 threads
    int orig = (t < nb) ? bsum[t] : 0;
    int v = orig;
    #pragma unroll
    for (int off = 1; off < 64; off <<= 1){
        int x = __shfl_up(v, off, 64);
        if (t >= off) v += x;
    }
    if (t < nb) bsum[t] = v - orig;           // exclusive
}

// stage 3: add block offsets; set offs[n] = E (constant: every edge lands in [0,n))
__global__ __launch_bounds__(1024) void add_off_kernel(
        int* __restrict__ offs, const int* __restrict__ bsum, int n){
    int i = blockIdx.x * 1024 + threadIdx.x;
    if (i < n) offs[i] += bsum[blockIdx.x];
    if (i == 0) offs[n] = N_EDGES;
}

__global__ void fill_kernel(const int* __restrict__ src, const int* __restrict__ dst,
                            const int* __restrict__ offs, int* __restrict__ cursor,
                            int* __restrict__ nbr, int E){
    int i = blockIdx.x * blockDim.x + threadIdx.x;
    if (i < E){
        int d = dst[i];
        int p = atomicAdd(&cursor[d], 1);
        nbr[offs[d] + p] = src[i];
    }
}

// ---------- dtype conversion ----------
__global__ void f2b_kernel(const float4* __restrict__ in, ushort4* __restrict__ out, int n4){
    int i = blockIdx.x * blockDim.x + threadIdx.x;
    if (i < n4){
        float4 v = in[i];
        ushort4 o; o.x = f2b(v.x); o.y = f2b(v.y); o.z = f2b(v.z); o.w = f2b(v.w);
        out[i] = o;
    }
}

// W [K,N] fp32 -> Wt [N,K] bf16 (coalesced writes)
__global__ void wtrans_kernel(const float* __restrict__ W, ushort_t* __restrict__ Wt,
                              int K, int N){
    int i = blockIdx.x * blockDim.x + threadIdx.x;   // i = n*K + k
    if (i < K * N){
        int n = i / K, k = i - n * K;
        Wt[i] = f2b(W[k * N + n]);
    }
}

// ---------- GEMM: C[M,N] = A[M,K] @ Bt[N,K]^T, bf16, 128x256 block tile ----------
__device__ __forceinline__ void load16(const void* g, void* l){
    __builtin_amdgcn_global_load_lds((const __attribute__((address_space(1))) void*)g,
                                     (__attribute__((address_space(3))) void*)l, 16, 0, 0);
}

// block tile 128(M) x 256(N), BK=32. 4 waves in 2x2: wave tile 64x128.
// grid: (MPAD/128, N/256). Requires N % 256 == 0.
__global__ __launch_bounds__(256, 2) void gemm_bt(const ushort_t* __restrict__ A,
                                                  const ushort_t* __restrict__ Bt,
                                                  ushort_t* __restrict__ C,
                                                  int N, int K){
    __shared__ ushort_t As[128 * 32];   // 8 KB
    __shared__ ushort_t Bs[256 * 32];   // 16 KB
    const int tid  = threadIdx.x, lane = tid & 63, wave = tid >> 6;
    const int bm = blockIdx.x, bn = blockIdx.y;
    const int fr = lane & 15;           // fragment row within 16
    const int fk = (lane >> 4) * 8;     // fragment k-offset within 32
    const int wm = (wave >> 1) * 64, wn = (wave & 1) * 128;
    f32x4 acc[4][8] = {};

    for (int kt = 0; kt < K; kt += 32){
        __syncthreads();
        // A: 512 slots of 16B; B: 1024 slots. slot s -> row s>>2, col (s&3)*8
        #pragma unroll
        for (int i = 0; i < 2; i++){
            int s = tid + i * 256;
            load16(A + (size_t)(bm * 128 + (s >> 2)) * K + kt + (s & 3) * 8,
                   (char*)As + s * 16);
        }
        #pragma unroll
        for (int i = 0; i < 4; i++){
            int s = tid + i * 256;
            load16(Bt + (size_t)(bn * 256 + (s >> 2)) * K + kt + (s & 3) * 8,
                   (char*)Bs + s * 16);
        }
        __syncthreads();   // drains vmcnt(0): global_load_lds complete
        bf16x8 af[4], bf[8];
        #pragma unroll
        for (int t = 0; t < 4; t++)
            af[t] = *(const bf16x8*)(const void*)(As + (wm + t * 16 + fr) * 32 + fk);
        #pragma unroll
        for (int t = 0; t < 8; t++)
            bf[t] = *(const bf16x8*)(const void*)(Bs + (wn + t * 16 + fr) * 32 + fk);
        #pragma unroll
        for (int tm = 0; tm < 4; tm++)
            #pragma unroll
            for (int tn = 0; tn < 8; tn++)
                acc[tm][tn] = __builtin_amdgcn_mfma_f32_16x16x32_bf16(
                                  af[tm], bf[tn], acc[tm][tn], 0, 0, 0);
    }
    // epilogue: C/D layout col=lane&15, row=(lane>>4)*4+reg  [m89-verified]
    const int r0 = (lane >> 4) * 4, c0 = lane & 15;
    #pragma unroll
    for (int tm = 0; tm < 4; tm++){
        #pragma unroll
        for (int tn = 0; tn < 8; tn++){
            int rbase = bm * 128 + wm + tm * 16 + r0;
            int cidx  = bn * 256 + wn + tn * 16 + c0;
            #pragma unroll
            for (int reg = 0; reg < 4; reg++)
                C[(size_t)(rbase + reg) * N + cidx] = f2b(acc[tm][tn][reg]);
        }
    }
}

// ---------- aggregation (wave-per-node, 16B/lane, 8-edge unrolled) ----------
__device__ __forceinline__ void acc8(float* a, uint4 y){
    a[0] += b2f((ushort_t)(y.x & 0xffff)); a[1] += b2f((ushort_t)(y.x >> 16));
    a[2] += b2f((ushort_t)(y.y & 0xffff)); a[3] += b2f((ushort_t)(y.y >> 16));
    a[4] += b2f((ushort_t)(y.z & 0xffff)); a[5] += b2f((ushort_t)(y.z >> 16));
    a[6] += b2f((ushort_t)(y.w & 0xffff)); a[7] += b2f((ushort_t)(y.w >> 16));
}
__device__ __forceinline__ void acc4(float* a, uint2 y){
    a[0] += b2f((ushort_t)(y.x & 0xffff)); a[1] += b2f((ushort_t)(y.x >> 16));
    a[2] += b2f((ushort_t)(y.y & 0xffff)); a[3] += b2f((ushort_t)(y.y >> 16));
}

// H[v] = relu((sum Y[nbr] + Y[v]) / (deg+1) + b), d=512, bf16 out
// wave per node: lane covers elems [lane*8, lane*8+8)
__global__ __launch_bounds__(256) void agg_relu_kernel(
        const ushort_t* __restrict__ Y, const int* __restrict__ offs,
        const int* __restrict__ nbr, const float* __restrict__ bias,
        ushort_t* __restrict__ H){
    const int lane = threadIdx.x & 63, wave = threadIdx.x >> 6;
    const int v = blockIdx.x * 4 + wave;
    const int off = lane * 8;
    float a[8];
    {   uint4 y = *(const uint4*)(const void*)(Y + (size_t)v * 512 + off);
        a[0] = b2f((ushort_t)(y.x & 0xffff)); a[1] = b2f((ushort_t)(y.x >> 16));
        a[2] = b2f((ushort_t)(y.y & 0xffff)); a[3] = b2f((ushort_t)(y.y >> 16));
        a[4] = b2f((ushort_t)(y.z & 0xffff)); a[5] = b2f((ushort_t)(y.z >> 16));
        a[6] = b2f((ushort_t)(y.w & 0xffff)); a[7] = b2f((ushort_t)(y.w >> 16)); }
    const int beg = offs[v], end = offs[v + 1];
    int i = beg;
    for (; i + 8 <= end; i += 8){
        uint4 yy[8];
        #pragma unroll
        for (int j = 0; j < 8; j++){
            int u = nbr[i + j];
            yy[j] = *(const uint4*)(const void*)(Y + (size_t)u * 512 + off);
        }
        #pragma unroll
        for (int j = 0; j < 8; j++) acc8(a, yy[j]);
    }
    for (; i + 4 <= end; i += 4){
        uint4 yy[4];
        #pragma unroll
        for (int j = 0; j < 4; j++){
            int u = nbr[i + j];
            yy[j] = *(const uint4*)(const void*)(Y + (size_t)u * 512 + off);
        }
        #pragma unroll
        for (int j = 0; j < 4; j++) acc8(a, yy[j]);
    }
    for (; i < end; i++){
        int u = nbr[i];
        uint4 y = *(const uint4*)(const void*)(Y + (size_t)u * 512 + off);
        acc8(a, y);
    }
    const float inv = 1.0f / (float)(end - beg + 1);
    float4 bb0 = ((const float4*)bias)[lane * 2];
    float4 bb1 = ((const float4*)bias)[lane * 2 + 1];
    float r[8];
    r[0] = a[0]*inv + bb0.x; r[1] = a[1]*inv + bb0.y;
    r[2] = a[2]*inv + bb0.z; r[3] = a[3]*inv + bb0.w;
    r[4] = a[4]*inv + bb1.x; r[5] = a[5]*inv + bb1.y;
    r[6] = a[6]*inv + bb1.z; r[7] = a[7]*inv + bb1.w;
    #pragma unroll
    for (int j = 0; j < 8; j++) r[j] = r[j] > 0.f ? r[j] : 0.f;
    uint4 o;
    o.x = (uint_t)f2b(r[0]) | ((uint_t)f2b(r[1]) << 16);
    o.y = (uint_t)f2b(r[2]) | ((uint_t)f2b(r[3]) << 16);
    o.z = (uint_t)f2b(r[4]) | ((uint_t)f2b(r[5]) << 16);
    o.w = (uint_t)f2b(r[6]) | ((uint_t)f2b(r[7]) << 16);
    *(uint4*)(void*)(H + (size_t)v * 512 + off) = o;
}

// final layer: d=256, fp32 out, no relu. wave per node, lane covers 4 elems (8B in, 16B out)
__global__ __launch_bounds__(256) void agg_out_kernel(
        const ushort_t* __restrict__ Y, const int* __restrict__ offs,
        const int* __restrict__ nbr, const float* __restrict__ bias,
        float* __restrict__ out){
    const int lane = threadIdx.x & 63, wave = threadIdx.x >> 6;
    const int v = blockIdx.x * 4 + wave;
    const int off = lane * 4;
    float a[4];
    {   uint2 y = *(const uint2*)(const void*)(Y + (size_t)v * 256 + off);
        a[0] = b2f((ushort_t)(y.x & 0xffff)); a[1] = b2f((ushort_t)(y.x >> 16));
        a[2] = b2f((ushort_t)(y.y & 0xffff)); a[3] = b2f((ushort_t)(y.y >> 16)); }
    const int beg = offs[v], end = offs[v + 1];
    int i = beg;
    for (; i + 8 <= end; i += 8){
        uint2 yy[8];
        #pragma unroll
        for (int j = 0; j < 8; j++){
            int u = nbr[i + j];
            yy[j] = *(const uint2*)(const void*)(Y + (size_t)u * 256 + off);
        }
        #pragma unroll
        for (int j = 0; j < 8; j++) acc4(a, yy[j]);
    }
    for (; i + 4 <= end; i += 4){
        uint2 yy[4];
        #pragma unroll
        for (int j = 0; j < 4; j++){
            int u = nbr[i + j];
            yy[j] = *(const uint2*)(const void*)(Y + (size_t)u * 256 + off);
        }
        #pragma unroll
        for (int j = 0; j < 4; j++) acc4(a, yy[j]);
    }
    for (; i < end; i++){
        int u = nbr[i];
        uint2 y = *(const uint2*)(const void*)(Y + (size_t)u * 256 + off);
        acc4(a, y);
    }
    const float inv = 1.0f / (float)(end - beg + 1);
    float4 bb = ((const float4*)bias)[lane];
    float4 r;
    r.x = a[0]*inv + bb.x; r.y = a[1]*inv + bb.y;
    r.z = a[2]*inv + bb.z; r.w = a[3]*inv + bb.w;
    ((float4*)out)[v * 64 + lane] = r;
}

extern "C" void kernel_launch(void* const* d_in, const int* in_sizes, int n_in,
                              void* d_out, int out_size, void* d_ws, size_t ws_size,
                              hipStream_t stream) {
    const float* feats = (const float*)d_in[0];
    const int*   src   = (const int*)  d_in[1];
    const int*   dst   = (const int*)  d_in[2];
    const float* W0    = (const float*)d_in[3];
    const float* b0    = (const float*)d_in[4];
    const float* W1    = (const float*)d_in[5];
    const float* b1    = (const float*)d_in[6];
    const float* W2    = (const float*)d_in[7];
    const float* b2    = (const float*)d_in[8];
    float* out = (float*)d_out;

    char* w = (char*)d_ws;
    ushort_t* Abuf = (ushort_t*)w;  w += (size_t)MPAD * 512 * 2;   // 51.25 MB
    ushort_t* Ybuf = (ushort_t*)w;  w += (size_t)MPAD * 512 * 2;   // 51.25 MB
    ushort_t* W0t  = (ushort_t*)w;  w += 512 * 512 * 2;
    ushort_t* W1t  = (ushort_t*)w;  w += 512 * 512 * 2;
    ushort_t* W2t  = (ushort_t*)w;  w += 256 * 512 * 2;
    int* deg    = (int*)w;          w += 50048 * 4;
    int* offs   = (int*)w;          w += 50056 * 4;
    int* cursor = (int*)w;          w += 50048 * 4;
    int* nbr    = (int*)w;          w += (size_t)N_EDGES * 4;
    int* bsum   = (int*)w;          w += 64 * 4;
    // total ~106 MB

    // CSR build (re-done every launch; ws is poisoned)
    zero_two<<<(N_NODES + 255) / 256, 256, 0, stream>>>(deg, cursor, N_NODES);
    hist_kernel<<<(N_EDGES + 255) / 256, 256, 0, stream>>>(dst, deg, N_EDGES);
    blk_scan_kernel<<<SCAN_B, 1024, 0, stream>>>(deg, offs, bsum, N_NODES);
    bsum_scan_kernel<<<1, 64, 0, stream>>>(bsum, SCAN_B);
    add_off_kernel<<<SCAN_B, 1024, 0, stream>>>(offs, bsum, N_NODES);
    fill_kernel<<<(N_EDGES + 255) / 256, 256, 0, stream>>>(src, dst, offs, cursor, nbr, N_EDGES);

    // conversions
    int n4 = N_NODES * 512 / 4;
    f2b_kernel<<<(n4 + 255) / 256, 256, 0, stream>>>((const float4*)feats, (ushort4*)Abuf, n4);
    wtrans_kernel<<<(512 * 512 + 255) / 256, 256, 0, stream>>>(W0, W0t, 512, 512);
    wtrans_kernel<<<(512 * 512 + 255) / 256, 256, 0, stream>>>(W1, W1t, 512, 512);
    wtrans_kernel<<<(512 * 256 + 255) / 256, 256, 0, stream>>>(W2, W2t, 512, 256);

    dim3 g01(MPAD / 128, 512 / 256);   // 128x256 tiles
    dim3 g2 (MPAD / 128, 256 / 256);

    // layer 0: Y = A @ W0t^T ; A' = relu((agg Y + Y)/(deg+1) + b0)
    gemm_bt<<<g01, 256, 0, stream>>>(Abuf, W0t, Ybuf, 512, 512);
    agg_relu_kernel<<<N_NODES / 4, 256, 0, stream>>>(Ybuf, offs, nbr, b0, Abuf);
    // layer 1
    gemm_bt<<<g01, 256, 0, stream>>>(Abuf, W1t, Ybuf, 512, 512);
    agg_relu_kernel<<<N_NODES / 4, 256, 0, stream>>>(Ybuf, offs, nbr, b1, Abuf);
    // layer 2 (no relu, fp32 out)
    gemm_bt<<<g2, 256, 0, stream>>>(Abuf, W2t, Ybuf, 256, 512);
    agg_out_kernel<<<N_NODES / 4, 256, 0, stream>>>(Ybuf, offs, nbr, b2, out);
}